// Round 5
// baseline (395.751 us; speedup 1.0000x reference)
//
#include <hip/hip_runtime.h>
#include <math.h>

// Problem constants
#define T_DIM 16
#define B_DIM 128
#define N_DIM 2048
#define TB    (T_DIM * B_DIM)   // 2048 rows of the GEMM

// Workspace layout (bytes). h is f32 (16MB used of 32MB reserved).
#define WS_H      0
#define WS_PSUM   35651584      // [32][2048] f64 per-rowband col sums
#define WS_PSUM2  36175872      // [32][2048] f64 per-rowband col sq-sums
#define WS_SSUM   36700160      // [2048] f64 row sums

typedef __attribute__((ext_vector_type(4))) double d4;

// ---- MFMA f64 wiring probe helpers ----------------------------------------
__device__ __forceinline__ double probeA(int m, int k) {
    return (double)((m * 7 + k * 13) % 23 - 11);
}
__device__ __forceinline__ double probeB(int k, int n) {
    return (double)((k * 5 + n * 3) % 19 - 9);
}

// In-kernel probe: every block derives the MFMA wiring hypothesis itself.
// Hypothesis encoding fh = ab*4 + dF;  ab = aF + 2*bF.
//  A-form 0: m=l&15,k=l>>4   1: m=l>>2,k=l&3
//  B-form 0: n=l&15,k=l>>4   1: n=l>>2,k=l&3
//  D-form 0: i=4*(l>>4)+r,j=l&15   1: i=(l>>4)+4r,j=l&15
//         2: j=4*(l>>4)+r,i=l&15   3: j=(l>>4)+4r,i=l&15
__device__ unsigned int run_probe(double* Cref, int l) {
    int i0 = l >> 2, j0 = (l & 3) << 2;
    for (int jj = 0; jj < 4; ++jj) {
        double s = 0.0;
        for (int k = 0; k < 4; ++k) s += probeA(i0, k) * probeB(k, j0 + jj);
        Cref[i0 * 16 + j0 + jj] = s;
    }
    __syncthreads();
    unsigned int win = 0xFFFFFFFFu;
    for (int ab = 0; ab < 4; ++ab) {
        int aF = ab & 1, bF = (ab >> 1) & 1;
        int mA = aF ? (l >> 2) : (l & 15);
        int kA = aF ? (l & 3)  : (l >> 4);
        int nB = bF ? (l >> 2) : (l & 15);
        int kB = bF ? (l & 3)  : (l >> 4);
        d4 d = (d4)0.0;
        d = __builtin_amdgcn_mfma_f64_16x16x4f64(probeA(mA, kA), probeB(kB, nB), d, 0, 0, 0);
        for (int dF = 0; dF < 4; ++dF) {
            double err = 0.0;
            for (int r = 0; r < 4; ++r) {
                int ii, jj;
                if (dF == 0)      { ii = 4 * (l >> 4) + r; jj = l & 15; }
                else if (dF == 1) { ii = (l >> 4) + 4 * r; jj = l & 15; }
                else if (dF == 2) { jj = 4 * (l >> 4) + r; ii = l & 15; }
                else              { jj = (l >> 4) + 4 * r; ii = l & 15; }
                err = fmax(err, fabs(d[r] - Cref[ii * 16 + jj]));
            }
            for (int off = 1; off < 64; off <<= 1)
                err = fmax(err, __shfl_xor(err, off, 64));
            if (err < 1e-9 && win == 0xFFFFFFFFu)
                win = (unsigned)(ab * 4 + dF);
        }
    }
    return win;
}

// ---- GEMM h[row,m] = sum_n x[row,n] * W[m,n] ------------------------------
// v15: vectorized staging, done right this time. k-interleaved-by-4 LDS
// layout: element (k,m) at word (k>>2)*320 + 4m + (k&3).
//  - stage: lane's float4 (k=4j..4j+3, m=lane) is ONE ds_write_b128 at
//    j*320+4*lane (contiguous region -> conflict-free). 8 writes/stage
//    vs 64 scalar in v14 -- shrinks the aligned staging stall window.
//  - read: A(4jq+kA, 16f+mA) at jq*320 + 64f + (4*mA+kA). Bank =
//    (4mA+kA)%32; 64 lanes cover residues 0..63 -> exactly 2-way = free,
//    for BOTH probe wiring forms. Per-lane base (4mA+kA) is one VGPR; all
//    read offsets are compile-time immediates (no R3 offset-array spill).
// Tile footprint 1280 words = 5120B, identical buffer offsets to v14.
// Everything else (compute order, epilogue, probe, rsum, fallback) is v14.
#define BK 16
#define SDD 68    // f64 vector-fallback stride (doubles)

#define MFMA_LOAD(koff)                                             \
    _Pragma("unroll")                                               \
    for (int j = 0; j < 4; ++j) {                                   \
        sa[j] = *(const float4*)(Ag + (koff) + 4 * j);              \
        sb[j] = *(const float4*)(Bg + (koff) + 4 * j);              \
    }

#define MFMA_STAGE(Ab, Bb)                                          \
    _Pragma("unroll")                                               \
    for (int j = 0; j < 4; ++j) {                                   \
        *(float4*)&(Ab)[j * 320 + 4 * lane] = sa[j];                \
        *(float4*)&(Bb)[j * 320 + 4 * lane] = sb[j];                \
    }                                                               \
    if (do_rsum) {                                                  \
        _Pragma("unroll")                                           \
        for (int j = 0; j < 4; ++j)                                 \
            rsum += (double)sa[j].x + (double)sa[j].y +             \
                    (double)sa[j].z + (double)sa[j].w;              \
    }

#define MFMA_COMPUTE(Ab, Bb)                                        \
    _Pragma("unroll")                                               \
    for (int jq = 0; jq < 4; ++jq) {                                \
        double av[4], bv[4];                                        \
        _Pragma("unroll")                                           \
        for (int f = 0; f < 4; ++f)                                 \
            av[f] = (double)(Ab)[jq * 320 + 64 * f + abase];        \
        _Pragma("unroll")                                           \
        for (int g = 0; g < 4; ++g)                                 \
            bv[g] = (double)(Bb)[jq * 320 + 64 * g + bbase];        \
        _Pragma("unroll")                                           \
        for (int f = 0; f < 4; ++f)                                 \
            _Pragma("unroll")                                       \
            for (int g = 0; g < 4; ++g)                             \
                acc[f][g] = __builtin_amdgcn_mfma_f64_16x16x4f64(   \
                    av[f], bv[g], acc[f][g], 0, 0, 0);              \
    }

__global__ __launch_bounds__(128, 2)
void gemm_hybrid(const float* __restrict__ A, const float* __restrict__ Bw,
                 float* __restrict__ C, double* __restrict__ psum,
                 double* __restrict__ psum2, double* __restrict__ ssum_out) {
    __shared__ __align__(16) char smem[40960];   // 2 waves x 2 bufs x 10240B; cbuf 32KB
    const int t    = threadIdx.x;
    const int lane = t & 63;
    const int w    = t >> 6;
    const int row0 = blockIdx.y * 64;
    const int col0 = blockIdx.x * 64;
    const int band = blockIdx.y;
    const bool do_rsum = (blockIdx.x == 0);

    // in-block probe (uses cbuf region; dead before staging starts)
    const unsigned int fh = run_probe((double*)smem, lane);
    __syncthreads();

    const float* Ag = A  + (size_t)(row0 + lane) * N_DIM;
    const float* Bg = Bw + (size_t)(col0 + lane) * N_DIM;
    const int kw = w * BK;
    double* cbuf = (double*)smem;                // 4096 doubles = 32KB
    double* rbuf = (double*)(smem + 32768);      // 64 doubles (row-sum xchg)
    double rsum = 0.0;

    if (fh <= 15u) {
        // ================= MFMA path =================
        const int dF = fh & 3, ab = fh >> 2;
        const int aF = ab & 1, bF = (ab >> 1) & 1;
        const int mA = aF ? (lane >> 2) : (lane & 15);
        const int kA = aF ? (lane & 3)  : (lane >> 4);
        const int nB = bF ? (lane >> 2) : (lane & 15);
        const int kB = bF ? (lane & 3)  : (lane >> 4);
        const int abase = 4 * mA + kA;   // one reg; read offsets are immediates
        const int bbase = 4 * nB + kB;
        int iD[4], jD[4];
#pragma unroll
        for (int r = 0; r < 4; ++r) {
            if (dF == 0)      { iD[r] = 4 * (lane >> 4) + r; jD[r] = lane & 15; }
            else if (dF == 1) { iD[r] = (lane >> 4) + 4 * r; jD[r] = lane & 15; }
            else if (dF == 2) { jD[r] = 4 * (lane >> 4) + r; iD[r] = lane & 15; }
            else              { jD[r] = (lane >> 4) + 4 * r; iD[r] = lane & 15; }
        }

        float* A0 = (float*)(smem + (size_t)w * 20480);  // 1280 words/tile
        float* B0 = A0 + 1280;
        float* A1 = A0 + 2560;
        float* B1 = A0 + 3840;

        d4 acc[4][4];
#pragma unroll
        for (int f = 0; f < 4; ++f)
#pragma unroll
            for (int g = 0; g < 4; ++g) acc[f][g] = (d4)0.0;

        float4 sa[4], sb[4];
        MFMA_LOAD(kw)                 // tile 0
        MFMA_STAGE(A0, B0)            // -> buf0
        MFMA_LOAD(kw + 32)            // tile 1

        for (int k0 = kw; k0 < N_DIM; k0 += 64) {
            MFMA_STAGE(A1, B1)        // tile k0+32 -> buf1
            if (k0 + 64 < N_DIM) { MFMA_LOAD(k0 + 64) }
            MFMA_COMPUTE(A0, B0)      // tile k0
            if (k0 + 64 < N_DIM) {
                MFMA_STAGE(A0, B0)    // tile k0+64 -> buf0
                if (k0 + 96 < N_DIM) { MFMA_LOAD(k0 + 96) }
            }
            MFMA_COMPUTE(A1, B1)      // tile k0+32
        }

        __syncthreads();
        if (w == 1) {
#pragma unroll
            for (int f = 0; f < 4; ++f)
#pragma unroll
                for (int g = 0; g < 4; ++g)
#pragma unroll
                    for (int r = 0; r < 4; ++r)
                        cbuf[((f * 4 + g) * 4 + r) * 64 + lane] = acc[f][g][r];
            if (do_rsum) rbuf[lane] = rsum;
        }
        __syncthreads();
        if (w == 0) {
#pragma unroll
            for (int f = 0; f < 4; ++f)
#pragma unroll
                for (int g = 0; g < 4; ++g)
#pragma unroll
                    for (int r = 0; r < 4; ++r)
                        acc[f][g][r] += cbuf[((f * 4 + g) * 4 + r) * 64 + lane];
            // store C (f32)
#pragma unroll
            for (int f = 0; f < 4; ++f)
#pragma unroll
                for (int r = 0; r < 4; ++r) {
                    int row = row0 + 16 * f + iD[r];
                    float* Crow = C + (size_t)row * N_DIM + col0 + jD[r];
#pragma unroll
                    for (int g = 0; g < 4; ++g)
                        Crow[16 * g] = (float)acc[f][g][r];
                }
            // layout-agnostic BN partials: scatter acc -> cbuf[row][col],
            // then column-sum (same-wave DS ordering -> no barrier needed)
#pragma unroll
            for (int f = 0; f < 4; ++f)
#pragma unroll
                for (int r = 0; r < 4; ++r)
#pragma unroll
                    for (int g = 0; g < 4; ++g)
                        cbuf[(16 * f + iD[r]) * 64 + 16 * g + jD[r]] = acc[f][g][r];
            double s = 0.0, q = 0.0;
#pragma unroll
            for (int r = 0; r < 64; ++r) {
                double v = cbuf[r * 64 + lane];
                s += v;
                q = fma(v, v, q);
            }
            psum [band * N_DIM + col0 + lane] = s;
            psum2[band * N_DIM + col0 + lane] = q;
            if (do_rsum) ssum_out[row0 + lane] = rsum + rbuf[lane];
        }
    } else {
        // ================= f64 VALU fallback (probe-fail only) =================
        const int tx = lane & 7;
        const int ty = lane >> 3;
        double* Asd = (double*)smem + (size_t)w * 2176;  // 16 x 68 doubles
        double* Bsd = Asd + 1088;

        double acc[8][8];
#pragma unroll
        for (int i = 0; i < 8; ++i)
#pragma unroll
            for (int j = 0; j < 8; ++j) acc[i][j] = 0.0;

        float4 sa[4], sb[4];
#pragma unroll
        for (int j = 0; j < 4; ++j) {
            sa[j] = *(const float4*)(Ag + kw + 4 * j);
            sb[j] = *(const float4*)(Bg + kw + 4 * j);
        }
        for (int k0 = kw; k0 < N_DIM; k0 += 2 * BK) {
#pragma unroll
            for (int j = 0; j < 4; ++j) {
                Asd[(4 * j + 0) * SDD + lane] = (double)sa[j].x;
                Asd[(4 * j + 1) * SDD + lane] = (double)sa[j].y;
                Asd[(4 * j + 2) * SDD + lane] = (double)sa[j].z;
                Asd[(4 * j + 3) * SDD + lane] = (double)sa[j].w;
                Bsd[(4 * j + 0) * SDD + lane] = (double)sb[j].x;
                Bsd[(4 * j + 1) * SDD + lane] = (double)sb[j].y;
                Bsd[(4 * j + 2) * SDD + lane] = (double)sb[j].z;
                Bsd[(4 * j + 3) * SDD + lane] = (double)sb[j].w;
            }
            if (do_rsum) {
#pragma unroll
                for (int j = 0; j < 4; ++j)
                    rsum += (double)sa[j].x + (double)sa[j].y +
                            (double)sa[j].z + (double)sa[j].w;
            }
            if (k0 + 2 * BK < N_DIM) {
#pragma unroll
                for (int j = 0; j < 4; ++j) {
                    sa[j] = *(const float4*)(Ag + k0 + 2 * BK + 4 * j);
                    sb[j] = *(const float4*)(Bg + k0 + 2 * BK + 4 * j);
                }
            }
#pragma unroll
            for (int k = 0; k < BK; ++k) {
                double a[8], b[8];
#pragma unroll
                for (int e = 0; e < 4; ++e) {
                    a[e]     = Asd[k * SDD + 4 * ty + e];
                    a[e + 4] = Asd[k * SDD + 32 + 4 * ty + e];
                    b[e]     = Bsd[k * SDD + 4 * tx + e];
                    b[e + 4] = Bsd[k * SDD + 32 + 4 * tx + e];
                }
#pragma unroll
                for (int i = 0; i < 8; ++i)
#pragma unroll
                    for (int j = 0; j < 8; ++j)
                        acc[i][j] = fma(a[i], b[j], acc[i][j]);
            }
        }

        __syncthreads();
        if (w == 1) {
#pragma unroll
            for (int e = 0; e < 64; ++e)
                cbuf[e * 64 + lane] = acc[e >> 3][e & 7];
            if (do_rsum) rbuf[lane] = rsum;
        }
        __syncthreads();
        if (w == 0) {
#pragma unroll
            for (int i = 0; i < 8; ++i)
#pragma unroll
                for (int j = 0; j < 8; ++j)
                    acc[i][j] += cbuf[(i * 8 + j) * 64 + lane];
#pragma unroll
            for (int i = 0; i < 8; ++i) {
                int r = row0 + ((i < 4) ? (4 * ty + i) : (32 + 4 * ty + i - 4));
                float* Crow = C + (size_t)r * N_DIM + col0;
#pragma unroll
                for (int jg = 0; jg < 2; ++jg) {
                    int cbase = (jg == 0) ? (4 * tx) : (32 + 4 * tx);
                    float4 v;
                    v.x = (float)acc[i][4 * jg + 0]; v.y = (float)acc[i][4 * jg + 1];
                    v.z = (float)acc[i][4 * jg + 2]; v.w = (float)acc[i][4 * jg + 3];
                    *(float4*)(Crow + cbase) = v;
                }
            }
            // BN partials via cbuf scatter + column reduction
#pragma unroll
            for (int i = 0; i < 8; ++i) {
                int rr = (i < 4) ? (4 * ty + i) : (32 + 4 * ty + i - 4);
#pragma unroll
                for (int j = 0; j < 8; ++j) {
                    int cc = (j < 4) ? (4 * tx + j) : (32 + 4 * tx + j - 4);
                    cbuf[rr * 64 + cc] = acc[i][j];
                }
            }
            double s = 0.0, q = 0.0;
#pragma unroll
            for (int r = 0; r < 64; ++r) {
                double v = cbuf[r * 64 + lane];
                s += v;
                q = fma(v, v, q);
            }
            psum [band * N_DIM + col0 + lane] = s;
            psum2[band * N_DIM + col0 + lane] = q;
            if (do_rsum) ssum_out[row0 + lane] = rsum + rbuf[lane];
        }
    }
}

// ---- fused BN-final + BN-apply + temporal-sum + triple LIF + output -------
__global__ __launch_bounds__(256)
void fused_lif_kernel(const float* __restrict__ x, const float* __restrict__ h,
                      const double* __restrict__ psum, const double* __restrict__ psum2,
                      const float* __restrict__ gamma, const float* __restrict__ beta,
                      const double* __restrict__ ssum, float* __restrict__ out) {
    int idx = blockIdx.x * 256 + threadIdx.x;
    int n = idx & (N_DIM - 1);
    int b = idx >> 11;
    // BN scale/shift for this column
    double s = 0.0, s2 = 0.0;
#pragma unroll
    for (int c = 0; c < 32; ++c) {
        s  += psum [c * N_DIM + n];
        s2 += psum2[c * N_DIM + n];
    }
    double mean = s * (1.0 / 2048.0);
    double var  = s2 * (1.0 / 2048.0) - mean * mean;
    double istd = 1.0 / sqrt(var + 1e-5);
    double sc = istd * (double)gamma[n];
    double sh = (double)beta[n] - mean * sc;
    // temporal sum (ascending t, f64)
    float xv[T_DIM];
    double ts = 0.0;
#pragma unroll
    for (int t = 0; t < T_DIM; ++t) {
        xv[t] = x[(size_t)(t * B_DIM + b) * N_DIM + n];
        ts += (double)xv[t];
    }
    double v1 = 0.0, v2 = 0.0, v3 = 0.0;
#pragma unroll
    for (int t = 0; t < T_DIM; ++t) {
        size_t off = (size_t)(t * B_DIM + b) * N_DIM + n;
        double hv = fma((double)h[off], sc, sh);
        v1 = v1 * 0.5 + hv;
        bool s1 = (v1 >= 1.0); if (s1) v1 = 0.0;
        double in2 = s1 ? ssum[t * B_DIM + b] : 0.0;
        v2 = v2 * 0.5 + in2;
        bool s2b = (v2 >= 1.0); if (s2b) v2 = 0.0;
        double in3 = s1 ? ts : 0.0;
        v3 = v3 * 0.5 + in3;
        bool s3 = (v3 >= 1.0); if (s3) v3 = 0.0;
        out[off] = xv[t] + ((s2b && s3) ? 1.0f : 0.0f);
    }
}

extern "C" void kernel_launch(void* const* d_in, const int* in_sizes, int n_in,
                              void* d_out, int out_size, void* d_ws, size_t ws_size,
                              hipStream_t stream) {
    const float* x     = (const float*)d_in[0];   // [16,128,2048]
    const float* W     = (const float*)d_in[1];   // [2048,2048]
    const float* gamma = (const float*)d_in[2];   // [2048]
    const float* beta  = (const float*)d_in[3];   // [2048]
    float* out = (float*)d_out;

    char* ws = (char*)d_ws;
    float*  h     = (float*)(ws + WS_H);
    double* psum  = (double*)(ws + WS_PSUM);
    double* psum2 = (double*)(ws + WS_PSUM2);
    double* ssum  = (double*)(ws + WS_SSUM);

    gemm_hybrid<<<dim3(N_DIM / 64, TB / 64), 128, 0, stream>>>(x, W, h, psum, psum2, ssum);
    fused_lif_kernel<<<(B_DIM * N_DIM) / 256, 256, 0, stream>>>(
        x, h, psum, psum2, gamma, beta, ssum, out);
}

// Round 6
// 378.409 us; speedup vs baseline: 1.0458x; 1.0458x over previous
//
#include <hip/hip_runtime.h>
#include <math.h>

// Problem constants
#define T_DIM 16
#define B_DIM 128
#define N_DIM 2048
#define TB    (T_DIM * B_DIM)   // 2048 rows of the GEMM

// Workspace layout (bytes). h is f32 (16MB used of 32MB reserved).
#define WS_H      0
#define WS_PSUM   35651584      // [32][2048] f64 per-rowband col sums
#define WS_PSUM2  36175872      // [32][2048] f64 per-rowband col sq-sums
#define WS_SSUM   36700160      // [2048] f64 row sums

typedef __attribute__((ext_vector_type(4))) double d4;

// ---- MFMA f64 wiring probe helpers ----------------------------------------
__device__ __forceinline__ double probeA(int m, int k) {
    return (double)((m * 7 + k * 13) % 23 - 11);
}
__device__ __forceinline__ double probeB(int k, int n) {
    return (double)((k * 5 + n * 3) % 19 - 9);
}

// In-kernel probe: every block derives the MFMA wiring hypothesis itself.
// Hypothesis encoding fh = ab*4 + dF;  ab = aF + 2*bF.
//  A-form 0: m=l&15,k=l>>4   1: m=l>>2,k=l&3
//  B-form 0: n=l&15,k=l>>4   1: n=l>>2,k=l&3
//  D-form 0: i=4*(l>>4)+r,j=l&15   1: i=(l>>4)+4r,j=l&15
//         2: j=4*(l>>4)+r,i=l&15   3: j=(l>>4)+4r,i=l&15
__device__ unsigned int run_probe(double* Cref, int l) {
    int i0 = l >> 2, j0 = (l & 3) << 2;
    for (int jj = 0; jj < 4; ++jj) {
        double s = 0.0;
        for (int k = 0; k < 4; ++k) s += probeA(i0, k) * probeB(k, j0 + jj);
        Cref[i0 * 16 + j0 + jj] = s;
    }
    __syncthreads();
    unsigned int win = 0xFFFFFFFFu;
    for (int ab = 0; ab < 4; ++ab) {
        int aF = ab & 1, bF = (ab >> 1) & 1;
        int mA = aF ? (l >> 2) : (l & 15);
        int kA = aF ? (l & 3)  : (l >> 4);
        int nB = bF ? (l >> 2) : (l & 15);
        int kB = bF ? (l & 3)  : (l >> 4);
        d4 d = (d4)0.0;
        d = __builtin_amdgcn_mfma_f64_16x16x4f64(probeA(mA, kA), probeB(kB, nB), d, 0, 0, 0);
        for (int dF = 0; dF < 4; ++dF) {
            double err = 0.0;
            for (int r = 0; r < 4; ++r) {
                int ii, jj;
                if (dF == 0)      { ii = 4 * (l >> 4) + r; jj = l & 15; }
                else if (dF == 1) { ii = (l >> 4) + 4 * r; jj = l & 15; }
                else if (dF == 2) { jj = 4 * (l >> 4) + r; ii = l & 15; }
                else              { jj = (l >> 4) + 4 * r; ii = l & 15; }
                err = fmax(err, fabs(d[r] - Cref[ii * 16 + jj]));
            }
            for (int off = 1; off < 64; off <<= 1)
                err = fmax(err, __shfl_xor(err, off, 64));
            if (err < 1e-9 && win == 0xFFFFFFFFu)
                win = (unsigned)(ab * 4 + dF);
        }
    }
    return win;
}

// ---- GEMM h[row,m] = sum_n x[row,n] * W[m,n] ------------------------------
// v16: 4-wave N-split. Block = 64x64 tile, 256 threads; wave wv owns the
// 64x16 column strip [col0+16*wv, +16). Diagnosis from R3/R5: ds_write_b128
// staging + 128-reg split-K accumulator = guaranteed scratch spill (150MB+
// WRITE_SIZE both rounds); bank-conflict counter delta was a b128 artifact
// (identical 2^23 in both layouts), reads were fine. Fix: shrink acc to
// 4x d4 = 32 regs via N-split. Gains: b128 staging fits (no spill),
// 16 waves/CU (4 blocks x 4 waves; LDS 34KB), no cross-wave reduction
// epilogue. Cost: 1 barrier per 32-k tile (64 total) -- hidden by 4
// mutually-unsynchronized blocks per CU.
// LDS: k-interleaved tile (k,m) at word (k>>2)*256 + 4m + (k&3).
//  stage: thread writes quads kq=wv and wv+4 at row m=lane: 4 ds_write_b128.
//  read:  A-frag at s*256 + 64f + (4mA+kA): lanes cover residues 0..63 ->
//         2/bank = free. B-frag at 2048 + s*256 + 64wv + (4nB+kB): same.
#define BK 32
#define NT (N_DIM / BK)   // 64 k-tiles

#define LOADT(tt)                                                   \
    {                                                               \
        const float* ap = Ag + (tt) * BK;                           \
        const float* bp = Bg + (tt) * BK;                           \
        a0 = *(const float4*)(ap);                                  \
        a1 = *(const float4*)(ap + 16);                             \
        b0 = *(const float4*)(bp);                                  \
        b1 = *(const float4*)(bp + 16);                             \
    }

#define STAGE(dst)                                                  \
    {                                                               \
        *(float4*)((dst) + wv * 256 + 4 * lane) = a0;               \
        *(float4*)((dst) + (wv + 4) * 256 + 4 * lane) = a1;         \
        *(float4*)((dst) + 2048 + wv * 256 + 4 * lane) = b0;        \
        *(float4*)((dst) + 2048 + (wv + 4) * 256 + 4 * lane) = b1;  \
        if (do_rsum)                                                \
            rsum += (double)a0.x + (double)a0.y + (double)a0.z +    \
                    (double)a0.w + (double)a1.x + (double)a1.y +    \
                    (double)a1.z + (double)a1.w;                    \
    }

#define CMFMA(cb)                                                   \
    _Pragma("unroll")                                               \
    for (int s = 0; s < 8; ++s) {                                   \
        double av0 = (double)(cb)[s * 256 + abase];                 \
        double av1 = (double)(cb)[s * 256 + 64 + abase];            \
        double av2 = (double)(cb)[s * 256 + 128 + abase];           \
        double av3 = (double)(cb)[s * 256 + 192 + abase];           \
        double bv  = (double)(cb)[2048 + s * 256 + 64 * wv + bbase];\
        acc[0] = __builtin_amdgcn_mfma_f64_16x16x4f64(av0, bv, acc[0], 0, 0, 0); \
        acc[1] = __builtin_amdgcn_mfma_f64_16x16x4f64(av1, bv, acc[1], 0, 0, 0); \
        acc[2] = __builtin_amdgcn_mfma_f64_16x16x4f64(av2, bv, acc[2], 0, 0, 0); \
        acc[3] = __builtin_amdgcn_mfma_f64_16x16x4f64(av3, bv, acc[3], 0, 0, 0); \
    }

#define CVALU(cb)                                                   \
    _Pragma("unroll")                                               \
    for (int s = 0; s < 8; ++s)                                     \
        _Pragma("unroll")                                           \
        for (int kk = 0; kk < 4; ++kk) {                            \
            double bvv = (double)(cb)[2048 + s * 256 + 64 * wv + 4 * (lane & 15) + kk]; \
            _Pragma("unroll")                                       \
            for (int rr = 0; rr < 16; ++rr) {                       \
                double avv = (double)(cb)[s * 256 + 4 * (16 * (lane >> 4) + rr) + kk]; \
                accv[rr] = fma(avv, bvv, accv[rr]);                 \
            }                                                       \
        }

__global__ __launch_bounds__(256, 4)
void gemm_hybrid(const float* __restrict__ A, const float* __restrict__ Bw,
                 float* __restrict__ C, double* __restrict__ psum,
                 double* __restrict__ psum2, double* __restrict__ ssum_out) {
    __shared__ __align__(16) char smem[34816];   // 2 bufs x 16KB + rbuf 2KB
    const int tid  = threadIdx.x;
    const int lane = tid & 63;
    const int wv   = tid >> 6;
    const int row0 = blockIdx.y * 64;
    const int col0 = blockIdx.x * 64;
    const int band = blockIdx.y;
    const bool do_rsum = (blockIdx.x == 0);

    // in-block probe (uses staging region; dead before staging starts)
    const unsigned int fh = run_probe((double*)smem, lane);
    __syncthreads();

    float*  sf   = (float*)smem;                 // 8192 words staging
    double* rbuf = (double*)(smem + 32768);      // 256 doubles

    const float* Ag = A  + (size_t)(row0 + lane) * N_DIM + 4 * wv;
    const float* Bg = Bw + (size_t)(col0 + lane) * N_DIM + 4 * wv;

    double rsum = 0.0;
    float4 a0, a1, b0, b1;

    if (fh <= 15u) {
        // ================= MFMA path =================
        const int dF = fh & 3, ab = fh >> 2;
        const int aF = ab & 1, bF = (ab >> 1) & 1;
        const int mA = aF ? (lane >> 2) : (lane & 15);
        const int kA = aF ? (lane & 3)  : (lane >> 4);
        const int nB = bF ? (lane >> 2) : (lane & 15);
        const int kB = bF ? (lane & 3)  : (lane >> 4);
        const int abase = 4 * mA + kA;
        const int bbase = 4 * nB + kB;
        int iD[4], jD[4];
#pragma unroll
        for (int r = 0; r < 4; ++r) {
            if (dF == 0)      { iD[r] = 4 * (lane >> 4) + r; jD[r] = lane & 15; }
            else if (dF == 1) { iD[r] = (lane >> 4) + 4 * r; jD[r] = lane & 15; }
            else if (dF == 2) { jD[r] = 4 * (lane >> 4) + r; iD[r] = lane & 15; }
            else              { jD[r] = (lane >> 4) + 4 * r; iD[r] = lane & 15; }
        }

        d4 acc[4];
#pragma unroll
        for (int f = 0; f < 4; ++f) acc[f] = (d4)0.0;

        LOADT(0)
        STAGE(sf)                    // tile 0 -> buf0
        LOADT(1)
        __syncthreads();

        for (int t = 0; t < NT; ++t) {
            float* cb = sf + (t & 1) * 4096;
            float* nb = sf + ((t + 1) & 1) * 4096;
            if (t + 1 < NT) { STAGE(nb) }
            if (t + 2 < NT) { LOADT(t + 2) }
            CMFMA(cb)
            __syncthreads();
        }

        // epilogue: C store + per-wave BN scatter (layout-agnostic)
        double* region = (double*)smem + wv * 1024;   // 64x16 doubles
#pragma unroll
        for (int f = 0; f < 4; ++f)
#pragma unroll
            for (int r = 0; r < 4; ++r) {
                region[(16 * f + iD[r]) * 16 + jD[r]] = acc[f][r];
                C[(size_t)(row0 + 16 * f + iD[r]) * N_DIM + col0 + 16 * wv + jD[r]]
                    = (float)acc[f][r];
            }
    } else {
        // ================= f64 VALU fallback (probe-fail only) =================
        // lane owns rows 16*(lane>>4)+rr (rr=0..15), col (lane&15) of strip.
        double accv[16];
#pragma unroll
        for (int rr = 0; rr < 16; ++rr) accv[rr] = 0.0;

        LOADT(0)
        STAGE(sf)
        LOADT(1)
        __syncthreads();

        for (int t = 0; t < NT; ++t) {
            float* cb = sf + (t & 1) * 4096;
            float* nb = sf + ((t + 1) & 1) * 4096;
            if (t + 1 < NT) { STAGE(nb) }
            if (t + 2 < NT) { LOADT(t + 2) }
            CVALU(cb)
            __syncthreads();
        }

        double* region = (double*)smem + wv * 1024;
#pragma unroll
        for (int rr = 0; rr < 16; ++rr) {
            int row = 16 * (lane >> 4) + rr;
            region[row * 16 + (lane & 15)] = accv[rr];
            C[(size_t)(row0 + row) * N_DIM + col0 + 16 * wv + (lane & 15)]
                = (float)accv[rr];
        }
    }

    rbuf[tid] = rsum;
    __syncthreads();

    // per-wave column stats from the private region (same-wave DS ordering)
    {
        double* region = (double*)smem + wv * 1024;
        const int c = lane & 15, rq = lane >> 4;
        double s = 0.0, q = 0.0;
#pragma unroll
        for (int rr = 0; rr < 16; ++rr) {
            double v = region[(16 * rq + rr) * 16 + c];
            s += v;
            q = fma(v, v, q);
        }
        s += __shfl_xor(s, 16, 64); s += __shfl_xor(s, 32, 64);
        q += __shfl_xor(q, 16, 64); q += __shfl_xor(q, 32, 64);
        if (lane < 16) {
            psum [band * N_DIM + col0 + 16 * wv + lane] = s;
            psum2[band * N_DIM + col0 + 16 * wv + lane] = q;
        }
    }
    if (do_rsum && wv == 0)
        ssum_out[row0 + lane] = (rbuf[lane] + rbuf[64 + lane])
                              + (rbuf[128 + lane] + rbuf[192 + lane]);
}

// ---- fused BN-final + BN-apply + temporal-sum + triple LIF + output -------
__global__ __launch_bounds__(256)
void fused_lif_kernel(const float* __restrict__ x, const float* __restrict__ h,
                      const double* __restrict__ psum, const double* __restrict__ psum2,
                      const float* __restrict__ gamma, const float* __restrict__ beta,
                      const double* __restrict__ ssum, float* __restrict__ out) {
    int idx = blockIdx.x * 256 + threadIdx.x;
    int n = idx & (N_DIM - 1);
    int b = idx >> 11;
    // BN scale/shift for this column
    double s = 0.0, s2 = 0.0;
#pragma unroll
    for (int c = 0; c < 32; ++c) {
        s  += psum [c * N_DIM + n];
        s2 += psum2[c * N_DIM + n];
    }
    double mean = s * (1.0 / 2048.0);
    double var  = s2 * (1.0 / 2048.0) - mean * mean;
    double istd = 1.0 / sqrt(var + 1e-5);
    double sc = istd * (double)gamma[n];
    double sh = (double)beta[n] - mean * sc;
    // temporal sum (ascending t, f64)
    float xv[T_DIM];
    double ts = 0.0;
#pragma unroll
    for (int t = 0; t < T_DIM; ++t) {
        xv[t] = x[(size_t)(t * B_DIM + b) * N_DIM + n];
        ts += (double)xv[t];
    }
    double v1 = 0.0, v2 = 0.0, v3 = 0.0;
#pragma unroll
    for (int t = 0; t < T_DIM; ++t) {
        size_t off = (size_t)(t * B_DIM + b) * N_DIM + n;
        double hv = fma((double)h[off], sc, sh);
        v1 = v1 * 0.5 + hv;
        bool s1 = (v1 >= 1.0); if (s1) v1 = 0.0;
        double in2 = s1 ? ssum[t * B_DIM + b] : 0.0;
        v2 = v2 * 0.5 + in2;
        bool s2b = (v2 >= 1.0); if (s2b) v2 = 0.0;
        double in3 = s1 ? ts : 0.0;
        v3 = v3 * 0.5 + in3;
        bool s3 = (v3 >= 1.0); if (s3) v3 = 0.0;
        out[off] = xv[t] + ((s2b && s3) ? 1.0f : 0.0f);
    }
}

extern "C" void kernel_launch(void* const* d_in, const int* in_sizes, int n_in,
                              void* d_out, int out_size, void* d_ws, size_t ws_size,
                              hipStream_t stream) {
    const float* x     = (const float*)d_in[0];   // [16,128,2048]
    const float* W     = (const float*)d_in[1];   // [2048,2048]
    const float* gamma = (const float*)d_in[2];   // [2048]
    const float* beta  = (const float*)d_in[3];   // [2048]
    float* out = (float*)d_out;

    char* ws = (char*)d_ws;
    float*  h     = (float*)(ws + WS_H);
    double* psum  = (double*)(ws + WS_PSUM);
    double* psum2 = (double*)(ws + WS_PSUM2);
    double* ssum  = (double*)(ws + WS_SSUM);

    gemm_hybrid<<<dim3(N_DIM / 64, TB / 64), 256, 0, stream>>>(x, W, h, psum, psum2, ssum);
    fused_lif_kernel<<<(B_DIM * N_DIM) / 256, 256, 0, stream>>>(
        x, h, psum, psum2, gamma, beta, ssum, out);
}